// Round 8
// baseline (313.069 us; speedup 1.0000x reference)
//
#include <hip/hip_runtime.h>
#include <math.h>

// Problem constants (fixed by the reference):
#define B_  4
#define C_  256     // in/out channels
#define CI_ 128     // inter channels (attention head dim D)
#define N_  4096    // H*W

typedef short s16x8  __attribute__((ext_vector_type(8)));    // 8 bf16 (4 VGPRs)
typedef float f32x4  __attribute__((ext_vector_type(4)));    // 16x16 accumulator
typedef float f32x16 __attribute__((ext_vector_type(16)));   // 32x32 accumulator

// fp32 -> bf16 (RNE)
__device__ inline ushort f2bf(float f) {
    unsigned int u = __float_as_uint(f);
    u += 0x7FFF + ((u >> 16) & 1);
    return (ushort)(u >> 16);
}
__device__ inline float bf2f(ushort u) {
    return __uint_as_float(((unsigned int)u) << 16);
}

// LDS-only workgroup sync (no vmcnt drain; prefetch loads stay in flight).
__device__ inline void block_sync_lds() {
    asm volatile("s_waitcnt lgkmcnt(0)" ::: "memory");
    __builtin_amdgcn_s_barrier();
    asm volatile("" ::: "memory");
}
// Intra-wave LDS write->read ordering only.
__device__ inline void wave_lds_fence() {
    asm volatile("s_waitcnt lgkmcnt(0)" ::: "memory");
}

// ---------------------------------------------------------------------------
// x transpose+cast (y<4) fused with weight cast (y==4).
//   x [B][C][N] fp32 -> xT [B][N][C] bf16, tile 64c x 64n.
//   Wcat=[Wg;Wt;Wp] bf16, Wobf bf16, bcat fp32.
// Grid (64, 5, 4).
// ---------------------------------------------------------------------------
__global__ __launch_bounds__(256) void xtw_kernel(
    const float* __restrict__ x, ushort* __restrict__ xT,
    const float* __restrict__ Wg, const float* __restrict__ Wt,
    const float* __restrict__ Wp, const float* __restrict__ Wo,
    const float* __restrict__ bg, const float* __restrict__ bt,
    const float* __restrict__ bp,
    ushort* __restrict__ Wcat, ushort* __restrict__ Wobf,
    float* __restrict__ bcat)
{
    const int t = threadIdx.x;
    if (blockIdx.y == 4) {
        // weight cast: 256 blocks (x 0..63, z 0..3) x 256 threads x 2 iters
        int gi = (blockIdx.z * 64 + blockIdx.x) * 256 + t;
        #pragma unroll
        for (int i = gi; i < 131072; i += 65536) {
            if (i < 32768)       Wcat[i] = f2bf(Wg[i]);
            else if (i < 65536)  Wcat[i] = f2bf(Wt[i - 32768]);
            else if (i < 98304)  Wcat[i] = f2bf(Wp[i - 65536]);
            else                 Wobf[i - 98304] = f2bf(Wo[i - 98304]);
        }
        if (gi < 128)            bcat[gi] = bg[gi];
        else if (gi < 256)       bcat[gi] = bt[gi - 128];
        else if (gi < 384)       bcat[gi] = bp[gi - 256];
        return;
    }
    __shared__ ushort Ls[64][72];
    const int b = blockIdx.z, c0 = blockIdx.y * 64, n0 = blockIdx.x * 64;
    const float* xb = x + ((size_t)b * C_ + c0) * N_ + n0;
    #pragma unroll
    for (int r = 0; r < 4; r++) {
        int idx = t + 256 * r;
        int c = idx >> 4, n4 = (idx & 15) * 4;
        float4 v = *(const float4*)&xb[(size_t)c * N_ + n4];
        ushort4 o;
        o.x = f2bf(v.x); o.y = f2bf(v.y); o.z = f2bf(v.z); o.w = f2bf(v.w);
        *(ushort4*)&Ls[c][n4] = o;
    }
    __syncthreads();
    ushort* xTb = xT + ((size_t)b * N_ + n0) * C_ + c0;
    #pragma unroll
    for (int r = 0; r < 2; r++) {
        int idx = t + 256 * r;
        int n = idx >> 3, c8 = (idx & 7) * 8;
        ushort tmp[8];
        #pragma unroll
        for (int u = 0; u < 8; u++) tmp[u] = Ls[c8 + u][n];
        *(uint4*)&xTb[(size_t)n * C_ + c8] = *(uint4*)tmp;
    }
}

// ---------------------------------------------------------------------------
// Merged projection GEMM (bf16 MFMA, 16x16x32). Grid (N/64, 2, B).
// Super-slice ms covers 192 rows of Wcat; Xs staged ONCE per k-step (was 6x).
// Wave wv owns m-rows [48wv, 48wv+48) = 3 m-subtiles. Epilogue routes by
// mt = m>>6: 0..1 -> g [ci][n]; 2..3 -> tht [n][ci]; 4..5 -> pht [n][ci].
// ---------------------------------------------------------------------------
__global__ __launch_bounds__(256) void proj_kernel(
    const ushort* __restrict__ Wcat, const float* __restrict__ bcat,
    const ushort* __restrict__ xT,
    ushort* __restrict__ g, ushort* __restrict__ tht, ushort* __restrict__ pht)
{
    __shared__ ushort Ws[192][72];   // 27648 B
    __shared__ ushort Xs[64][72];    // 9216 B
    const int b = blockIdx.z, ms = blockIdx.y, n0 = blockIdx.x * 64;
    const int t = threadIdx.x, wv = t >> 6, lane = t & 63;
    const int g4 = lane >> 4, ln = lane & 15;
    const ushort* Wsrc = Wcat + (size_t)ms * 192 * C_;
    const ushort* Xsrc = xT + ((size_t)b * N_ + n0) * C_;

    f32x4 acc[3][4];
    #pragma unroll
    for (int i = 0; i < 3; i++)
        #pragma unroll
        for (int j = 0; j < 4; j++) acc[i][j] = (f32x4){0.f, 0.f, 0.f, 0.f};

    for (int k0 = 0; k0 < C_; k0 += 64) {
        block_sync_lds();
        #pragma unroll
        for (int r = 0; r < 8; r++) {
            int idx = t + 256 * r;
            if (idx < 1536) {
                int row = idx >> 3, k8 = (idx & 7) * 8;
                *(uint4*)&Ws[row][k8] = *(const uint4*)&Wsrc[(size_t)row * C_ + k0 + k8];
            } else {
                int j = idx - 1536;
                int row = j >> 3, k8 = (j & 7) * 8;
                *(uint4*)&Xs[row][k8] = *(const uint4*)&Xsrc[(size_t)row * C_ + k0 + k8];
            }
        }
        block_sync_lds();
        #pragma unroll
        for (int kk = 0; kk < 2; kk++) {
            s16x8 bX[4];
            #pragma unroll
            for (int nt = 0; nt < 4; nt++)
                bX[nt] = *(const s16x8*)&Xs[16 * nt + ln][32 * kk + 8 * g4];
            #pragma unroll
            for (int sm = 0; sm < 3; sm++) {
                s16x8 aW = *(const s16x8*)&Ws[48 * wv + 16 * sm + ln][32 * kk + 8 * g4];
                #pragma unroll
                for (int nt = 0; nt < 4; nt++)
                    acc[sm][nt] = __builtin_amdgcn_mfma_f32_16x16x32_bf16(aW, bX[nt], acc[sm][nt], 0, 0, 0);
            }
        }
    }

    #pragma unroll
    for (int sm = 0; sm < 3; sm++) {
        #pragma unroll
        for (int r = 0; r < 4; r++) {
            int m = ms * 192 + 48 * wv + 16 * sm + 4 * g4 + r;   // 0..383
            float bi = bcat[m];
            int mt = m >> 6;   // wave-uniform per (wv,sm)
            #pragma unroll
            for (int nt = 0; nt < 4; nt++) {
                float v = acc[sm][nt][r] + bi;
                int n = n0 + 16 * nt + ln;
                if (mt < 2)
                    g[(size_t)b * CI_ * N_ + (size_t)m * N_ + n] = f2bf(v);
                else if (mt < 4)
                    tht[(size_t)b * N_ * CI_ + (size_t)n * CI_ + (m - 128)] = f2bf(v);
                else
                    pht[(size_t)b * N_ * CI_ + (size_t)n * CI_ + (m - 256)] = f2bf(v);
            }
        }
    }
}

// ---------------------------------------------------------------------------
// MFMA flash attention, 32x32x16, j-split-across-waves for TLP.
// Block: Q-tile 64, J-tile 64; wave wv = (q-strip qs = wv&1) x (j-half jh = wv>>1):
// each wave computes S(32q x 32j), P, PV(32q x 128d) for its half -> per-iter
// chain HALVED vs round 5-7; grid (N/64, 4 chunks, B) = 1024 blocks; LDS 45 KB
// + launch_bounds(256,3) -> 3 blocks/CU = 12 waves/CU (was 8).
// O/l j-half partials combined in epilogue via LDS (fp32).
// No-max softmax; l via ones-MFMA; P LDS round-trip is wave-private.
// ---------------------------------------------------------------------------
#define SQK 136   // K row stride (bf16), 272 B
#define SPV 72    // V^T / P row stride (bf16), 144 B
#define JCHUNK 1024

__global__ __launch_bounds__(256, 3) void attn_mfma_kernel(
    const ushort* __restrict__ qn,   // [B][N][CI]
    const ushort* __restrict__ kn,   // [B][N][CI]
    const ushort* __restrict__ vm,   // [B][CI][N]
    ushort* __restrict__ Opart,      // [4][B][N][CI] bf16 (unnormalized)
    float* __restrict__ lbuf)        // [4][B][N] row sums
{
    __shared__ __align__(16) ushort smem[22528];   // 45056 B
    ushort* Ks = smem;                 // [64][SQK]  = 8704 elems
    ushort* Vt = smem + 8704;          // [128][SPV] = 9216 elems
    ushort* Ps = smem + 17920;         // [64][SPV]  = 4608 elems
    // epilogue aliases (after loop): Obuf f32[64][132] = 33792 B, Lb f32[64]

    const int b     = blockIdx.z;
    const int chunk = blockIdx.y;
    const int i0    = blockIdx.x * 64;
    const int jbase = chunk * JCHUNK;
    const int t     = threadIdx.x;
    const int wv    = t >> 6;
    const int lane  = t & 63;
    const int n32   = lane & 31;
    const int h     = lane >> 5;
    const int qs    = wv & 1;    // q-strip: q in [32qs, 32qs+32)
    const int jh    = wv >> 1;   // j-half:  j in [32jh, 32jh+32) of the tile

    const ushort* kb = kn + (size_t)b * N_ * CI_;
    const ushort* vb = vm + (size_t)b * CI_ * N_;

    // ---- aQ (A-operand) direct from global: row q = i0 + 32qs + n32
    s16x8 aQ[8];
    {
        const ushort* qrow = qn + ((size_t)b * N_ + i0 + 32 * qs + n32) * CI_ + 8 * h;
        #pragma unroll
        for (int kk = 0; kk < 8; kk++)
            aQ[kk] = *(const s16x8*)&qrow[16 * kk];
    }

    s16x8 vones;
    #pragma unroll
    for (int u = 0; u < 8; u++) vones[u] = (short)0x3F80;

    f32x16 Oacc[4], Lacc;
    #pragma unroll
    for (int dt = 0; dt < 4; dt++)
        #pragma unroll
        for (int e = 0; e < 16; e++) Oacc[dt][e] = 0.f;
    #pragma unroll
    for (int e = 0; e < 16; e++) Lacc[e] = 0.f;

    // ---- prefetch first j-tile (K 64x128, V 128x64; 4+4 uint4/thread)
    uint4 pfK[4], pfV[4];
    #pragma unroll
    for (int r = 0; r < 4; r++) {
        int idx = t + 256 * r;
        int row = idx >> 4, ch = idx & 15;
        pfK[r] = *(const uint4*)&kb[(size_t)(jbase + row) * CI_ + ch * 8];
    }
    #pragma unroll
    for (int r = 0; r < 4; r++) {
        int idx = t + 256 * r;
        int d = idx >> 3, ch = idx & 7;
        pfV[r] = *(const uint4*)&vb[(size_t)d * N_ + jbase + ch * 8];
    }

    for (int jt = jbase; jt < jbase + JCHUNK; jt += 64) {
        block_sync_lds();   // prev tile's LDS reads retired everywhere
        #pragma unroll
        for (int r = 0; r < 4; r++) {
            int idx = t + 256 * r;
            int row = idx >> 4, ch = idx & 15;
            *(uint4*)&Ks[row * SQK + ch * 8] = pfK[r];
        }
        #pragma unroll
        for (int r = 0; r < 4; r++) {
            int idx = t + 256 * r;
            int d = idx >> 3, ch = idx & 7;
            *(uint4*)&Vt[d * SPV + ch * 8] = pfV[r];
        }
        block_sync_lds();   // K/V visible

        if (jt + 64 < jbase + JCHUNK) {
            const ushort* ksrc = kb + (size_t)(jt + 64) * CI_;
            #pragma unroll
            for (int r = 0; r < 4; r++) {
                int idx = t + 256 * r;
                int row = idx >> 4, ch = idx & 15;
                pfK[r] = *(const uint4*)&ksrc[(size_t)row * CI_ + ch * 8];
            }
            #pragma unroll
            for (int r = 0; r < 4; r++) {
                int idx = t + 256 * r;
                int d = idx >> 3, ch = idx & 7;
                pfV[r] = *(const uint4*)&vb[(size_t)d * N_ + jt + 64 + ch * 8];
            }
        }

        // ---- S = Q K^T for this wave's (32q x 32j): 8 k-steps
        f32x16 S;
        #pragma unroll
        for (int e = 0; e < 16; e++) S[e] = 0.f;
        #pragma unroll
        for (int kk = 0; kk < 8; kk++) {
            s16x8 bK = *(const s16x8*)&Ks[(32 * jh + n32) * SQK + 16 * kk + 8 * h];
            S = __builtin_amdgcn_mfma_f32_32x32x16_bf16(aQ[kk], bK, S, 0, 0, 0);
        }

        // ---- P = exp(S) -> LDS [q][j] (wave-private region)
        #pragma unroll
        for (int rg = 0; rg < 16; rg++) {
            int R = (rg & 3) + 8 * (rg >> 2) + 4 * h;
            Ps[(32 * qs + R) * SPV + 32 * jh + n32] = f2bf(__expf(S[rg]));
        }
        wave_lds_fence();   // intra-wave P visibility

        // ---- aP + row sums + PV: O(32q x 128d) += P(32q x 32j) V^T(32j x 128d)
        s16x8 aP[2];
        #pragma unroll
        for (int kt = 0; kt < 2; kt++)
            aP[kt] = *(const s16x8*)&Ps[(32 * qs + n32) * SPV + 32 * jh + 16 * kt + 8 * h];
        Lacc = __builtin_amdgcn_mfma_f32_32x32x16_bf16(aP[0], vones, Lacc, 0, 0, 0);
        Lacc = __builtin_amdgcn_mfma_f32_32x32x16_bf16(aP[1], vones, Lacc, 0, 0, 0);
        #pragma unroll
        for (int dsub = 0; dsub < 4; dsub++) {
            #pragma unroll
            for (int kt = 0; kt < 2; kt++) {
                s16x8 bV = *(const s16x8*)&Vt[(32 * dsub + n32) * SPV + 32 * jh + 16 * kt + 8 * h];
                Oacc[dsub] = __builtin_amdgcn_mfma_f32_32x32x16_bf16(aP[kt], bV, Oacc[dsub], 0, 0, 0);
            }
        }
    }

    // ---- epilogue: combine j-halves via LDS, store unnormalized O + l
    block_sync_lds();   // loop LDS traffic fully retired; smem reused
    float* Obuf = (float*)smem;          // [64][132] fp32
    float* Lb   = Obuf + 64 * 132;       // [64] fp32
    if (jh == 0) {
        #pragma unroll
        for (int rg = 0; rg < 16; rg++) {
            int R = (rg & 3) + 8 * (rg >> 2) + 4 * h;
            int q = 32 * qs + R;
            #pragma unroll
            for (int dsub = 0; dsub < 4; dsub++)
                Obuf[q * 132 + 32 * dsub + n32] = Oacc[dsub][rg];
        }
        if (n32 == 0) {
            #pragma unroll
            for (int rg = 0; rg < 16; rg++) {
                int R = (rg & 3) + 8 * (rg >> 2) + 4 * h;
                Lb[32 * qs + R] = Lacc[rg];
            }
        }
    }
    block_sync_lds();
    if (jh == 1) {
        ushort* Ob = Opart + (size_t)chunk * (B_ * N_ * CI_) + ((size_t)b * N_ + i0) * CI_;
        #pragma unroll
        for (int rg = 0; rg < 16; rg++) {
            int R = (rg & 3) + 8 * (rg >> 2) + 4 * h;
            int q = 32 * qs + R;
            #pragma unroll
            for (int dsub = 0; dsub < 4; dsub++) {
                float v = Obuf[q * 132 + 32 * dsub + n32] + Oacc[dsub][rg];
                Ob[(size_t)q * CI_ + 32 * dsub + n32] = f2bf(v);
            }
        }
        if (n32 == 0) {
            #pragma unroll
            for (int rg = 0; rg < 16; rg++) {
                int R = (rg & 3) + 8 * (rg >> 2) + 4 * h;
                lbuf[((size_t)chunk * B_ + b) * N_ + i0 + 32 * qs + R] = Lb[32 * qs + R] + Lacc[rg];
            }
        }
    }
}

// ---------------------------------------------------------------------------
// Output GEMM (bf16 MFMA), M-tile 128, fused 4-chunk combine in staging.
// Grid (N/64, C/128, B).
// ---------------------------------------------------------------------------
__global__ __launch_bounds__(256) void outgemm_kernel(
    const ushort* __restrict__ Wobf, const float* __restrict__ bo,
    const ushort* __restrict__ Opart, const float* __restrict__ lbuf,
    const float* __restrict__ x, float* __restrict__ out)
{
    __shared__ ushort Ws[128][72];
    __shared__ ushort Ys[64][72];
    const int b = blockIdx.z, m0 = blockIdx.y * 128, n0 = blockIdx.x * 64;
    const int t = threadIdx.x, wv = t >> 6, lane = t & 63;
    const int g4 = lane >> 4, ln = lane & 15;
    const ushort* Wsrc = Wobf + (size_t)m0 * CI_;
    const size_t cs = (size_t)B_ * N_ * CI_;

    f32x4 acc[2][4];
    #pragma unroll
    for (int i = 0; i < 2; i++)
        #pragma unroll
        for (int j = 0; j < 4; j++) acc[i][j] = (f32x4){0.f, 0.f, 0.f, 0.f};

    for (int k0 = 0; k0 < CI_; k0 += 64) {
        block_sync_lds();
        #pragma unroll
        for (int r = 0; r < 4; r++) {
            int idx = t + 256 * r;
            int row = idx >> 3, k8 = (idx & 7) * 8;
            *(uint4*)&Ws[row][k8] = *(const uint4*)&Wsrc[(size_t)row * CI_ + k0 + k8];
        }
        #pragma unroll
        for (int r = 0; r < 2; r++) {
            int idx = t + 256 * r;
            int row = idx >> 3, k8 = (idx & 7) * 8;
            size_t obase = ((size_t)b * N_ + n0 + row) * CI_ + k0 + k8;
            float lsum = 0.f;
            #pragma unroll
            for (int c = 0; c < 4; c++)
                lsum += lbuf[((size_t)c * B_ + b) * N_ + n0 + row];
            float inv = 1.0f / lsum;
            ushort o0[8], o1[8], o2[8], o3[8], yo[8];
            *(uint4*)o0 = *(const uint4*)&Opart[obase];
            *(uint4*)o1 = *(const uint4*)&Opart[cs + obase];
            *(uint4*)o2 = *(const uint4*)&Opart[2 * cs + obase];
            *(uint4*)o3 = *(const uint4*)&Opart[3 * cs + obase];
            #pragma unroll
            for (int u = 0; u < 8; u++)
                yo[u] = f2bf((bf2f(o0[u]) + bf2f(o1[u]) + bf2f(o2[u]) + bf2f(o3[u])) * inv);
            *(uint4*)&Ys[row][k8] = *(uint4*)yo;
        }
        block_sync_lds();
        #pragma unroll
        for (int kk = 0; kk < 2; kk++) {
            #pragma unroll
            for (int sm = 0; sm < 2; sm++) {
                s16x8 aW = *(const s16x8*)&Ws[16 * (2 * wv + sm) + ln][32 * kk + 8 * g4];
                #pragma unroll
                for (int nt = 0; nt < 4; nt++) {
                    s16x8 bY = *(const s16x8*)&Ys[16 * nt + ln][32 * kk + 8 * g4];
                    acc[sm][nt] = __builtin_amdgcn_mfma_f32_16x16x32_bf16(aW, bY, acc[sm][nt], 0, 0, 0);
                }
            }
        }
    }

    float* outb = out + (size_t)b * C_ * N_;
    const float* xb = x + (size_t)b * C_ * N_;
    #pragma unroll
    for (int sm = 0; sm < 2; sm++) {
        #pragma unroll
        for (int r = 0; r < 4; r++) {
            int m = m0 + 16 * (2 * wv + sm) + 4 * g4 + r;
            float bi = bo[m];
            #pragma unroll
            for (int nt = 0; nt < 4; nt++) {
                size_t idx = (size_t)m * N_ + n0 + 16 * nt + ln;
                outb[idx] = acc[sm][nt][r] + bi + xb[idx];
            }
        }
    }
}

// ---------------------------------------------------------------------------
extern "C" void kernel_launch(void* const* d_in, const int* in_sizes, int n_in,
                              void* d_out, int out_size, void* d_ws, size_t ws_size,
                              hipStream_t stream) {
    const float* x  = (const float*)d_in[0];
    const float* Wg = (const float*)d_in[1];
    const float* bg = (const float*)d_in[2];
    const float* Wt = (const float*)d_in[3];
    const float* bt = (const float*)d_in[4];
    const float* Wp = (const float*)d_in[5];
    const float* bp = (const float*)d_in[6];
    const float* Wo = (const float*)d_in[7];
    const float* bo = (const float*)d_in[8];
    float* out = (float*)d_out;

    // ws layout (bytes). xT (8 MB) dead after proj; Opart (16 MB) aliases it.
    char* w = (char*)d_ws;
    ushort* xT    = (ushort*)w;                   // [B][N][C]  bf16, 8 MB
    ushort* Opart = (ushort*)w;                   // [4][B][N][CI] bf16, 16 MB
    ushort* g     = (ushort*)(w + 16777216);      // [B][CI][N] bf16, 4 MB
    ushort* tht   = (ushort*)(w + 20971520);      // [B][N][CI] bf16, 4 MB
    ushort* pht   = (ushort*)(w + 25165824);      // [B][N][CI] bf16, 4 MB
    ushort* Wcat  = (ushort*)(w + 29360128);      // [384][256] bf16
    ushort* Wobf  = (ushort*)(w + 29556736);      // [256][128] bf16
    float*  bcat  = (float*) (w + 29622272);      // [384]
    float*  lbuf  = (float*) (w + 29623808);      // [4][B][N] fp32, 256 KB

    dim3 blk(256);
    xtw_kernel<<<dim3(N_ / 64, 5, B_), blk, 0, stream>>>(
        x, xT, Wg, Wt, Wp, Wo, bg, bt, bp, Wcat, Wobf, bcat);
    proj_kernel<<<dim3(N_ / 64, 2, B_), blk, 0, stream>>>(Wcat, bcat, xT, g, tht, pht);
    attn_mfma_kernel<<<dim3(N_ / 64, 4, B_), blk, 0, stream>>>(tht, pht, g, Opart, lbuf);
    outgemm_kernel<<<dim3(N_ / 64, C_ / 128, B_), blk, 0, stream>>>(Wobf, bo, Opart, lbuf, x, out);
}

// Round 9
// 203.694 us; speedup vs baseline: 1.5370x; 1.5370x over previous
//
#include <hip/hip_runtime.h>
#include <math.h>

// Problem constants (fixed by the reference):
#define B_  4
#define C_  256     // in/out channels
#define CI_ 128     // inter channels (attention head dim D)
#define N_  4096    // H*W

typedef short s16x8  __attribute__((ext_vector_type(8)));    // 8 bf16 (4 VGPRs)
typedef float f32x4  __attribute__((ext_vector_type(4)));    // 16x16 accumulator
typedef float f32x16 __attribute__((ext_vector_type(16)));   // 32x32 accumulator

// fp32 -> bf16 (RNE)
__device__ inline ushort f2bf(float f) {
    unsigned int u = __float_as_uint(f);
    u += 0x7FFF + ((u >> 16) & 1);
    return (ushort)(u >> 16);
}
__device__ inline float bf2f(ushort u) {
    return __uint_as_float(((unsigned int)u) << 16);
}

// LDS-only workgroup sync (no vmcnt drain; prefetch loads stay in flight).
// The "memory" clobber also pins global-load ISSUE order: loads written
// BEFORE this barrier cannot sink past it.
__device__ inline void block_sync_lds() {
    asm volatile("s_waitcnt lgkmcnt(0)" ::: "memory");
    __builtin_amdgcn_s_barrier();
    asm volatile("" ::: "memory");
}
// Intra-wave LDS write->read ordering only.
__device__ inline void wave_lds_fence() {
    asm volatile("s_waitcnt lgkmcnt(0)" ::: "memory");
}

// ---------------------------------------------------------------------------
// x transpose+cast (y<4) fused with weight cast (y==4). Grid (64, 5, 4).
// ---------------------------------------------------------------------------
__global__ __launch_bounds__(256) void xtw_kernel(
    const float* __restrict__ x, ushort* __restrict__ xT,
    const float* __restrict__ Wg, const float* __restrict__ Wt,
    const float* __restrict__ Wp, const float* __restrict__ Wo,
    const float* __restrict__ bg, const float* __restrict__ bt,
    const float* __restrict__ bp,
    ushort* __restrict__ Wcat, ushort* __restrict__ Wobf,
    float* __restrict__ bcat)
{
    const int t = threadIdx.x;
    if (blockIdx.y == 4) {
        int gi = (blockIdx.z * 64 + blockIdx.x) * 256 + t;
        #pragma unroll
        for (int i = gi; i < 131072; i += 65536) {
            if (i < 32768)       Wcat[i] = f2bf(Wg[i]);
            else if (i < 65536)  Wcat[i] = f2bf(Wt[i - 32768]);
            else if (i < 98304)  Wcat[i] = f2bf(Wp[i - 65536]);
            else                 Wobf[i - 98304] = f2bf(Wo[i - 98304]);
        }
        if (gi < 128)            bcat[gi] = bg[gi];
        else if (gi < 256)       bcat[gi] = bt[gi - 128];
        else if (gi < 384)       bcat[gi] = bp[gi - 256];
        return;
    }
    __shared__ ushort Ls[64][72];
    const int b = blockIdx.z, c0 = blockIdx.y * 64, n0 = blockIdx.x * 64;
    const float* xb = x + ((size_t)b * C_ + c0) * N_ + n0;
    #pragma unroll
    for (int r = 0; r < 4; r++) {
        int idx = t + 256 * r;
        int c = idx >> 4, n4 = (idx & 15) * 4;
        float4 v = *(const float4*)&xb[(size_t)c * N_ + n4];
        ushort4 o;
        o.x = f2bf(v.x); o.y = f2bf(v.y); o.z = f2bf(v.z); o.w = f2bf(v.w);
        *(ushort4*)&Ls[c][n4] = o;
    }
    __syncthreads();
    ushort* xTb = xT + ((size_t)b * N_ + n0) * C_ + c0;
    #pragma unroll
    for (int r = 0; r < 2; r++) {
        int idx = t + 256 * r;
        int n = idx >> 3, c8 = (idx & 7) * 8;
        ushort tmp[8];
        #pragma unroll
        for (int u = 0; u < 8; u++) tmp[u] = Ls[c8 + u][n];
        *(uint4*)&xTb[(size_t)n * C_ + c8] = *(uint4*)tmp;
    }
}

// ---------------------------------------------------------------------------
// Merged projection GEMM (bf16 MFMA, 16x16x32). Grid (N/64, 2, B).
// Super-slice ms covers 192 rows of Wcat; Xs staged once per k-step.
// ---------------------------------------------------------------------------
__global__ __launch_bounds__(256) void proj_kernel(
    const ushort* __restrict__ Wcat, const float* __restrict__ bcat,
    const ushort* __restrict__ xT,
    ushort* __restrict__ g, ushort* __restrict__ tht, ushort* __restrict__ pht)
{
    __shared__ ushort Ws[192][72];
    __shared__ ushort Xs[64][72];
    const int b = blockIdx.z, ms = blockIdx.y, n0 = blockIdx.x * 64;
    const int t = threadIdx.x, wv = t >> 6, lane = t & 63;
    const int g4 = lane >> 4, ln = lane & 15;
    const ushort* Wsrc = Wcat + (size_t)ms * 192 * C_;
    const ushort* Xsrc = xT + ((size_t)b * N_ + n0) * C_;

    f32x4 acc[3][4];
    #pragma unroll
    for (int i = 0; i < 3; i++)
        #pragma unroll
        for (int j = 0; j < 4; j++) acc[i][j] = (f32x4){0.f, 0.f, 0.f, 0.f};

    for (int k0 = 0; k0 < C_; k0 += 64) {
        block_sync_lds();
        #pragma unroll
        for (int r = 0; r < 8; r++) {
            int idx = t + 256 * r;
            if (idx < 1536) {
                int row = idx >> 3, k8 = (idx & 7) * 8;
                *(uint4*)&Ws[row][k8] = *(const uint4*)&Wsrc[(size_t)row * C_ + k0 + k8];
            } else {
                int j = idx - 1536;
                int row = j >> 3, k8 = (j & 7) * 8;
                *(uint4*)&Xs[row][k8] = *(const uint4*)&Xsrc[(size_t)row * C_ + k0 + k8];
            }
        }
        block_sync_lds();
        #pragma unroll
        for (int kk = 0; kk < 2; kk++) {
            s16x8 bX[4];
            #pragma unroll
            for (int nt = 0; nt < 4; nt++)
                bX[nt] = *(const s16x8*)&Xs[16 * nt + ln][32 * kk + 8 * g4];
            #pragma unroll
            for (int sm = 0; sm < 3; sm++) {
                s16x8 aW = *(const s16x8*)&Ws[48 * wv + 16 * sm + ln][32 * kk + 8 * g4];
                #pragma unroll
                for (int nt = 0; nt < 4; nt++)
                    acc[sm][nt] = __builtin_amdgcn_mfma_f32_16x16x32_bf16(aW, bX[nt], acc[sm][nt], 0, 0, 0);
            }
        }
    }

    #pragma unroll
    for (int sm = 0; sm < 3; sm++) {
        #pragma unroll
        for (int r = 0; r < 4; r++) {
            int m = ms * 192 + 48 * wv + 16 * sm + 4 * g4 + r;   // 0..383
            float bi = bcat[m];
            int mt = m >> 6;
            #pragma unroll
            for (int nt = 0; nt < 4; nt++) {
                float v = acc[sm][nt][r] + bi;
                int n = n0 + 16 * nt + ln;
                if (mt < 2)
                    g[(size_t)b * CI_ * N_ + (size_t)m * N_ + n] = f2bf(v);
                else if (mt < 4)
                    tht[(size_t)b * N_ * CI_ + (size_t)n * CI_ + (m - 128)] = f2bf(v);
                else
                    pht[(size_t)b * N_ * CI_ + (size_t)n * CI_ + (m - 256)] = f2bf(v);
            }
        }
    }
}

// ---------------------------------------------------------------------------
// MFMA flash attention, 32x32x16 (round-6 structure, best measured).
// ONE change: next-tile prefetch is issued BETWEEN the LDS commit and
// barrier-2. The memory-clobbered barrier pins the loads there — they are
// guaranteed in flight across the whole compute phase (no compiler sinking).
// Q-tile 128 (wave owns q in [32wv,32wv+32)), J-tile 64, split-j 4 chunks.
// No-max softmax; l via ones-MFMA; P LDS round-trip wave-private.
// ---------------------------------------------------------------------------
#define SQK 136   // Q/K row stride (bf16), 272 B
#define SPV 72    // V^T / P row stride (bf16), 144 B
#define JCHUNK 1024

__global__ __launch_bounds__(256, 2) void attn_mfma_kernel(
    const ushort* __restrict__ qn,   // [B][N][CI]
    const ushort* __restrict__ kn,   // [B][N][CI]
    const ushort* __restrict__ vm,   // [B][CI][N]
    ushort* __restrict__ Opart,      // [4][B][N][CI] bf16 (unnormalized)
    float* __restrict__ lbuf)        // [4][B][N] row sums
{
    __shared__ __align__(16) ushort smem[35328];   // 70656 B
    ushort* Qs = smem;                 // [128][SQK] (staging only)
    ushort* Ps = smem;                 // [128][SPV] (aliases Qs after hoist)
    ushort* Ks = smem + 17408;         // [64][SQK]
    ushort* Vt = smem + 26112;         // [128][SPV]

    const int b     = blockIdx.z;
    const int chunk = blockIdx.y;
    const int i0    = blockIdx.x * 128;
    const int jbase = chunk * JCHUNK;
    const int t     = threadIdx.x;
    const int wv    = t >> 6;
    const int lane  = t & 63;
    const int n32   = lane & 31;
    const int h     = lane >> 5;

    const ushort* qb = qn + ((size_t)b * N_ + i0) * CI_;
    const ushort* kb = kn + (size_t)b * N_ * CI_;
    const ushort* vb = vm + (size_t)b * CI_ * N_;

    // ---- stage Q once
    #pragma unroll
    for (int r = 0; r < 8; r++) {
        int idx = t + 256 * r;
        int row = idx >> 4, ch = idx & 15;
        *(uint4*)&Qs[row * SQK + ch * 8] = *(const uint4*)&qb[(size_t)row * CI_ + ch * 8];
    }
    block_sync_lds();

    s16x8 aQ[8];
    #pragma unroll
    for (int kk = 0; kk < 8; kk++)
        aQ[kk] = *(const s16x8*)&Qs[(32 * wv + n32) * SQK + 16 * kk + 8 * h];

    s16x8 vones;
    #pragma unroll
    for (int u = 0; u < 8; u++) vones[u] = (short)0x3F80;

    f32x16 Oacc[4], Lacc;
    #pragma unroll
    for (int dt = 0; dt < 4; dt++)
        #pragma unroll
        for (int e = 0; e < 16; e++) Oacc[dt][e] = 0.f;
    #pragma unroll
    for (int e = 0; e < 16; e++) Lacc[e] = 0.f;

    // ---- prefetch first j-tile
    uint4 pfK[4], pfV[4];
    #pragma unroll
    for (int r = 0; r < 4; r++) {
        int idx = t + 256 * r;
        int row = idx >> 4, ch = idx & 15;
        pfK[r] = *(const uint4*)&kb[(size_t)(jbase + row) * CI_ + ch * 8];
    }
    #pragma unroll
    for (int r = 0; r < 4; r++) {
        int idx = t + 256 * r;
        int d = idx >> 3, ch = idx & 7;
        pfV[r] = *(const uint4*)&vb[(size_t)d * N_ + jbase + ch * 8];
    }

    for (int jt = jbase; jt < jbase + JCHUNK; jt += 64) {
        block_sync_lds();   // prev tile's LDS reads retired everywhere
        // commit prefetched tile (vmcnt wait lands here, ~1 compute-phase old)
        #pragma unroll
        for (int r = 0; r < 4; r++) {
            int idx = t + 256 * r;
            int row = idx >> 4, ch = idx & 15;
            *(uint4*)&Ks[row * SQK + ch * 8] = pfK[r];
        }
        #pragma unroll
        for (int r = 0; r < 4; r++) {
            int idx = t + 256 * r;
            int d = idx >> 3, ch = idx & 7;
            *(uint4*)&Vt[d * SPV + ch * 8] = pfV[r];
        }
        // issue NEXT tile's loads HERE, before barrier-2: the memory-clobbered
        // barrier forbids sinking them into the compute phase below.
        if (jt + 64 < jbase + JCHUNK) {
            const ushort* ksrc = kb + (size_t)(jt + 64) * CI_;
            #pragma unroll
            for (int r = 0; r < 4; r++) {
                int idx = t + 256 * r;
                int row = idx >> 4, ch = idx & 15;
                pfK[r] = *(const uint4*)&ksrc[(size_t)row * CI_ + ch * 8];
            }
            #pragma unroll
            for (int r = 0; r < 4; r++) {
                int idx = t + 256 * r;
                int d = idx >> 3, ch = idx & 7;
                pfV[r] = *(const uint4*)&vb[(size_t)d * N_ + jt + 64 + ch * 8];
            }
        }
        block_sync_lds();   // K/V visible; loads above are now in flight

        // ---- S = Q K^T : 2 j-subtiles of 32, K=128 in 8 steps
        f32x16 S0, S1;
        #pragma unroll
        for (int e = 0; e < 16; e++) { S0[e] = 0.f; S1[e] = 0.f; }
        #pragma unroll
        for (int kk = 0; kk < 8; kk++) {
            s16x8 bK0 = *(const s16x8*)&Ks[n32 * SQK + 16 * kk + 8 * h];
            s16x8 bK1 = *(const s16x8*)&Ks[(32 + n32) * SQK + 16 * kk + 8 * h];
            S0 = __builtin_amdgcn_mfma_f32_32x32x16_bf16(aQ[kk], bK0, S0, 0, 0, 0);
            S1 = __builtin_amdgcn_mfma_f32_32x32x16_bf16(aQ[kk], bK1, S1, 0, 0, 0);
        }

        // ---- P = exp(S) -> LDS [q][j] (conflict-free b16 writes)
        #pragma unroll
        for (int rg = 0; rg < 16; rg++) {
            int R = (rg & 3) + 8 * (rg >> 2) + 4 * h;
            int prow = (32 * wv + R) * SPV;
            Ps[prow + n32]      = f2bf(__expf(S0[rg]));
            Ps[prow + 32 + n32] = f2bf(__expf(S1[rg]));
        }
        wave_lds_fence();   // intra-wave P visibility

        // ---- PV + row sums
        s16x8 aP[4];
        #pragma unroll
        for (int kk = 0; kk < 4; kk++)
            aP[kk] = *(const s16x8*)&Ps[(32 * wv + n32) * SPV + 16 * kk + 8 * h];
        #pragma unroll
        for (int kk = 0; kk < 4; kk++)
            Lacc = __builtin_amdgcn_mfma_f32_32x32x16_bf16(aP[kk], vones, Lacc, 0, 0, 0);
        #pragma unroll
        for (int dt = 0; dt < 4; dt++) {
            #pragma unroll
            for (int kk = 0; kk < 4; kk++) {
                s16x8 bV = *(const s16x8*)&Vt[(32 * dt + n32) * SPV + 16 * kk + 8 * h];
                Oacc[dt] = __builtin_amdgcn_mfma_f32_32x32x16_bf16(aP[kk], bV, Oacc[dt], 0, 0, 0);
            }
        }
    }

    // ---- epilogue: unnormalized O -> [b][n][d] bf16; l -> lbuf
    ushort* Ob = Opart + (size_t)chunk * (B_ * N_ * CI_) + ((size_t)b * N_ + i0) * CI_;
    #pragma unroll
    for (int rg = 0; rg < 16; rg++) {
        int R = (rg & 3) + 8 * (rg >> 2) + 4 * h;
        int q = 32 * wv + R;
        #pragma unroll
        for (int dt = 0; dt < 4; dt++)
            Ob[(size_t)q * CI_ + 32 * dt + n32] = f2bf(Oacc[dt][rg]);
    }
    if (n32 == 0) {
        #pragma unroll
        for (int rg = 0; rg < 16; rg++) {
            int R = (rg & 3) + 8 * (rg >> 2) + 4 * h;
            lbuf[((size_t)chunk * B_ + b) * N_ + i0 + 32 * wv + R] = Lacc[rg];
        }
    }
}

// ---------------------------------------------------------------------------
// Output GEMM (bf16 MFMA), M-tile 128, fused 4-chunk combine in staging.
// Grid (N/64, C/128, B).
// ---------------------------------------------------------------------------
__global__ __launch_bounds__(256) void outgemm_kernel(
    const ushort* __restrict__ Wobf, const float* __restrict__ bo,
    const ushort* __restrict__ Opart, const float* __restrict__ lbuf,
    const float* __restrict__ x, float* __restrict__ out)
{
    __shared__ ushort Ws[128][72];
    __shared__ ushort Ys[64][72];
    const int b = blockIdx.z, m0 = blockIdx.y * 128, n0 = blockIdx.x * 64;
    const int t = threadIdx.x, wv = t >> 6, lane = t & 63;
    const int g4 = lane >> 4, ln = lane & 15;
    const ushort* Wsrc = Wobf + (size_t)m0 * CI_;
    const size_t cs = (size_t)B_ * N_ * CI_;

    f32x4 acc[2][4];
    #pragma unroll
    for (int i = 0; i < 2; i++)
        #pragma unroll
        for (int j = 0; j < 4; j++) acc[i][j] = (f32x4){0.f, 0.f, 0.f, 0.f};

    for (int k0 = 0; k0 < CI_; k0 += 64) {
        block_sync_lds();
        #pragma unroll
        for (int r = 0; r < 4; r++) {
            int idx = t + 256 * r;
            int row = idx >> 3, k8 = (idx & 7) * 8;
            *(uint4*)&Ws[row][k8] = *(const uint4*)&Wsrc[(size_t)row * CI_ + k0 + k8];
        }
        #pragma unroll
        for (int r = 0; r < 2; r++) {
            int idx = t + 256 * r;
            int row = idx >> 3, k8 = (idx & 7) * 8;
            size_t obase = ((size_t)b * N_ + n0 + row) * CI_ + k0 + k8;
            float lsum = 0.f;
            #pragma unroll
            for (int c = 0; c < 4; c++)
                lsum += lbuf[((size_t)c * B_ + b) * N_ + n0 + row];
            float inv = 1.0f / lsum;
            ushort o0[8], o1[8], o2[8], o3[8], yo[8];
            *(uint4*)o0 = *(const uint4*)&Opart[obase];
            *(uint4*)o1 = *(const uint4*)&Opart[cs + obase];
            *(uint4*)o2 = *(const uint4*)&Opart[2 * cs + obase];
            *(uint4*)o3 = *(const uint4*)&Opart[3 * cs + obase];
            #pragma unroll
            for (int u = 0; u < 8; u++)
                yo[u] = f2bf((bf2f(o0[u]) + bf2f(o1[u]) + bf2f(o2[u]) + bf2f(o3[u])) * inv);
            *(uint4*)&Ys[row][k8] = *(uint4*)yo;
        }
        block_sync_lds();
        #pragma unroll
        for (int kk = 0; kk < 2; kk++) {
            #pragma unroll
            for (int sm = 0; sm < 2; sm++) {
                s16x8 aW = *(const s16x8*)&Ws[16 * (2 * wv + sm) + ln][32 * kk + 8 * g4];
                #pragma unroll
                for (int nt = 0; nt < 4; nt++) {
                    s16x8 bY = *(const s16x8*)&Ys[16 * nt + ln][32 * kk + 8 * g4];
                    acc[sm][nt] = __builtin_amdgcn_mfma_f32_16x16x32_bf16(aW, bY, acc[sm][nt], 0, 0, 0);
                }
            }
        }
    }

    float* outb = out + (size_t)b * C_ * N_;
    const float* xb = x + (size_t)b * C_ * N_;
    #pragma unroll
    for (int sm = 0; sm < 2; sm++) {
        #pragma unroll
        for (int r = 0; r < 4; r++) {
            int m = m0 + 16 * (2 * wv + sm) + 4 * g4 + r;
            float bi = bo[m];
            #pragma unroll
            for (int nt = 0; nt < 4; nt++) {
                size_t idx = (size_t)m * N_ + n0 + 16 * nt + ln;
                outb[idx] = acc[sm][nt][r] + bi + xb[idx];
            }
        }
    }
}

// ---------------------------------------------------------------------------
extern "C" void kernel_launch(void* const* d_in, const int* in_sizes, int n_in,
                              void* d_out, int out_size, void* d_ws, size_t ws_size,
                              hipStream_t stream) {
    const float* x  = (const float*)d_in[0];
    const float* Wg = (const float*)d_in[1];
    const float* bg = (const float*)d_in[2];
    const float* Wt = (const float*)d_in[3];
    const float* bt = (const float*)d_in[4];
    const float* Wp = (const float*)d_in[5];
    const float* bp = (const float*)d_in[6];
    const float* Wo = (const float*)d_in[7];
    const float* bo = (const float*)d_in[8];
    float* out = (float*)d_out;

    // ws layout (bytes). xT (8 MB) dead after proj; Opart (16 MB) aliases it.
    char* w = (char*)d_ws;
    ushort* xT    = (ushort*)w;                   // [B][N][C]  bf16, 8 MB
    ushort* Opart = (ushort*)w;                   // [4][B][N][CI] bf16, 16 MB
    ushort* g     = (ushort*)(w + 16777216);      // [B][CI][N] bf16, 4 MB
    ushort* tht   = (ushort*)(w + 20971520);      // [B][N][CI] bf16, 4 MB
    ushort* pht   = (ushort*)(w + 25165824);      // [B][N][CI] bf16, 4 MB
    ushort* Wcat  = (ushort*)(w + 29360128);      // [384][256] bf16
    ushort* Wobf  = (ushort*)(w + 29556736);      // [256][128] bf16
    float*  bcat  = (float*) (w + 29622272);      // [384]
    float*  lbuf  = (float*) (w + 29623808);      // [4][B][N] fp32, 256 KB

    dim3 blk(256);
    xtw_kernel<<<dim3(N_ / 64, 5, B_), blk, 0, stream>>>(
        x, xT, Wg, Wt, Wp, Wo, bg, bt, bp, Wcat, Wobf, bcat);
    proj_kernel<<<dim3(N_ / 64, 2, B_), blk, 0, stream>>>(Wcat, bcat, xT, g, tht, pht);
    attn_mfma_kernel<<<dim3(N_ / 128, 4, B_), blk, 0, stream>>>(tht, pht, g, Opart, lbuf);
    outgemm_kernel<<<dim3(N_ / 64, C_ / 128, B_), blk, 0, stream>>>(Wobf, bo, Opart, lbuf, x, out);
}

// Round 10
// 195.804 us; speedup vs baseline: 1.5989x; 1.0403x over previous
//
#include <hip/hip_runtime.h>
#include <math.h>

// Problem constants (fixed by the reference):
#define B_  4
#define C_  256     // in/out channels
#define CI_ 128     // inter channels (attention head dim D)
#define N_  4096    // H*W

typedef short s16x8  __attribute__((ext_vector_type(8)));    // 8 bf16 (4 VGPRs)
typedef float f32x4  __attribute__((ext_vector_type(4)));    // 16x16 accumulator
typedef float f32x16 __attribute__((ext_vector_type(16)));   // 32x32 accumulator

// fp32 -> bf16 (RNE)
__device__ inline ushort f2bf(float f) {
    unsigned int u = __float_as_uint(f);
    u += 0x7FFF + ((u >> 16) & 1);
    return (ushort)(u >> 16);
}
__device__ inline float bf2f(ushort u) {
    return __uint_as_float(((unsigned int)u) << 16);
}

// LDS-only workgroup sync (no vmcnt drain; prefetch loads stay in flight).
__device__ inline void block_sync_lds() {
    asm volatile("s_waitcnt lgkmcnt(0)" ::: "memory");
    __builtin_amdgcn_s_barrier();
    asm volatile("" ::: "memory");
}

// ---------------------------------------------------------------------------
// Weight cast: Wcat = [Wg;Wt;Wp] bf16 (384x256), Wobf bf16 (256x128),
// bcat = [bg;bt;bp] fp32 (384). Grid 512x256.   (round-6 stack, measured best)
// ---------------------------------------------------------------------------
__global__ __launch_bounds__(256) void wcast_kernel(
    const float* __restrict__ Wg, const float* __restrict__ Wt,
    const float* __restrict__ Wp, const float* __restrict__ Wo,
    const float* __restrict__ bg, const float* __restrict__ bt,
    const float* __restrict__ bp,
    ushort* __restrict__ Wcat, ushort* __restrict__ Wobf,
    float* __restrict__ bcat)
{
    int i = blockIdx.x * 256 + threadIdx.x;
    if (i < 32768)       Wcat[i] = f2bf(Wg[i]);
    else if (i < 65536)  Wcat[i] = f2bf(Wt[i - 32768]);
    else if (i < 98304)  Wcat[i] = f2bf(Wp[i - 65536]);
    else if (i < 131072) Wobf[i - 98304] = f2bf(Wo[i - 98304]);
    if (i < 128)         bcat[i] = bg[i];
    else if (i < 256)    bcat[i] = bt[i - 128];
    else if (i < 384)    bcat[i] = bp[i - 256];
}

// ---------------------------------------------------------------------------
// x transpose+cast: x [B][C][N] fp32 -> xT [B][N][C] bf16. Tile 64c x 64n.
// ---------------------------------------------------------------------------
__global__ __launch_bounds__(256) void xt_kernel(
    const float* __restrict__ x, ushort* __restrict__ xT)
{
    __shared__ ushort Ls[64][72];
    const int b = blockIdx.z, c0 = blockIdx.y * 64, n0 = blockIdx.x * 64;
    const float* xb = x + ((size_t)b * C_ + c0) * N_ + n0;
    const int t = threadIdx.x;
    #pragma unroll
    for (int r = 0; r < 4; r++) {
        int idx = t + 256 * r;
        int c = idx >> 4, n4 = (idx & 15) * 4;
        float4 v = *(const float4*)&xb[(size_t)c * N_ + n4];
        ushort4 o;
        o.x = f2bf(v.x); o.y = f2bf(v.y); o.z = f2bf(v.z); o.w = f2bf(v.w);
        *(ushort4*)&Ls[c][n4] = o;
    }
    __syncthreads();
    ushort* xTb = xT + ((size_t)b * N_ + n0) * C_ + c0;
    #pragma unroll
    for (int r = 0; r < 2; r++) {
        int idx = t + 256 * r;
        int n = idx >> 3, c8 = (idx & 7) * 8;
        ushort tmp[8];
        #pragma unroll
        for (int u = 0; u < 8; u++) tmp[u] = Ls[c8 + u][n];
        *(uint4*)&xTb[(size_t)n * C_ + c8] = *(uint4*)tmp;
    }
}

// ---------------------------------------------------------------------------
// Fused projection GEMM (bf16 MFMA, 16x16x32). Grid (N/64, 6, B).
// (round-6 version — measured faster than the merged super-slice variant)
// ---------------------------------------------------------------------------
__global__ __launch_bounds__(256) void proj_kernel(
    const ushort* __restrict__ Wcat, const float* __restrict__ bcat,
    const ushort* __restrict__ xT,
    ushort* __restrict__ g, ushort* __restrict__ tht, ushort* __restrict__ pht)
{
    __shared__ ushort Ws[64][72];
    __shared__ ushort Xs[64][72];
    const int b = blockIdx.z, mt = blockIdx.y, n0 = blockIdx.x * 64;
    const int t = threadIdx.x, wv = t >> 6, lane = t & 63;
    const int g4 = lane >> 4, ln = lane & 15;
    const ushort* Wsrc = Wcat + (size_t)mt * 64 * C_;
    const ushort* Xsrc = xT + ((size_t)b * N_ + n0) * C_;

    f32x4 acc[4];
    #pragma unroll
    for (int i = 0; i < 4; i++) acc[i] = (f32x4){0.f, 0.f, 0.f, 0.f};

    for (int k0 = 0; k0 < C_; k0 += 64) {
        block_sync_lds();
        #pragma unroll
        for (int r = 0; r < 2; r++) {
            int idx = t + 256 * r;
            int row = idx >> 3, k8 = (idx & 7) * 8;
            *(uint4*)&Ws[row][k8] = *(const uint4*)&Wsrc[(size_t)row * C_ + k0 + k8];
            *(uint4*)&Xs[row][k8] = *(const uint4*)&Xsrc[(size_t)row * C_ + k0 + k8];
        }
        block_sync_lds();
        if (mt < 2) {
            #pragma unroll
            for (int kk = 0; kk < 2; kk++) {
                s16x8 aW = *(const s16x8*)&Ws[16 * wv + ln][32 * kk + 8 * g4];
                #pragma unroll
                for (int nt = 0; nt < 4; nt++) {
                    s16x8 bX = *(const s16x8*)&Xs[16 * nt + ln][32 * kk + 8 * g4];
                    acc[nt] = __builtin_amdgcn_mfma_f32_16x16x32_bf16(aW, bX, acc[nt], 0, 0, 0);
                }
            }
        } else {
            #pragma unroll
            for (int kk = 0; kk < 2; kk++) {
                s16x8 aX = *(const s16x8*)&Xs[16 * wv + ln][32 * kk + 8 * g4];
                #pragma unroll
                for (int ct = 0; ct < 4; ct++) {
                    s16x8 bW = *(const s16x8*)&Ws[16 * ct + ln][32 * kk + 8 * g4];
                    acc[ct] = __builtin_amdgcn_mfma_f32_16x16x32_bf16(aX, bW, acc[ct], 0, 0, 0);
                }
            }
        }
    }

    if (mt < 2) {
        ushort* ob = g + (size_t)b * CI_ * N_;
        #pragma unroll
        for (int r = 0; r < 4; r++) {
            int mloc = 16 * wv + 4 * g4 + r;
            float bi = bcat[mt * 64 + mloc];
            #pragma unroll
            for (int nt = 0; nt < 4; nt++)
                ob[(size_t)(mt * 64 + mloc) * N_ + n0 + 16 * nt + ln] = f2bf(acc[nt][r] + bi);
        }
    } else {
        ushort* ob = ((mt < 4) ? tht : pht) + (size_t)b * N_ * CI_;
        int cib = ((mt - 2) & 1) * 64;
        #pragma unroll
        for (int r = 0; r < 4; r++) {
            int nloc = 16 * wv + 4 * g4 + r;
            #pragma unroll
            for (int ct = 0; ct < 4; ct++) {
                float bi = bcat[mt * 64 + 16 * ct + ln];
                ob[(size_t)(n0 + nloc) * CI_ + cib + 16 * ct + ln] = f2bf(acc[ct][r] + bi);
            }
        }
    }
}

// ---------------------------------------------------------------------------
// MFMA flash attention, 32x32x16, PAIRED-WAVE B-REUSE.
// Wave pair pr owns q in [64pr, 64pr+64). Within a pair (dv = wv&1):
//   S phase : wave computes S(64q x 32j) for j-half jb0=32dv; each bK read
//             shared across 2 q-strips  -> 8 bK reads / 16 S-MFMA.
//   PV phase: wave computes O(64q x 64d) for d-half db0=64dv over ALL 64 j;
//             each bV read shared across 2 q-strips -> 8 aP + 8 bV / 16 MFMA.
// Per-wave LDS reads/iter: 36 -> 24 b128 (the measured bottleneck: LDS pipe
// at ~107 B/cyc ceiling). Cost: P is pair-shared -> 3rd barrier per iter.
// l (row sums) by even waves only (ones-MFMA over full j of the pair).
// Q-tile 128, J-tile 64, split-j 4 chunks, grid (32,4,4)=512, 2 blocks/CU.
// ---------------------------------------------------------------------------
#define SQK 136   // Q/K row stride (bf16), 272 B
#define SPV 72    // V^T / P row stride (bf16), 144 B
#define JCHUNK 1024

__global__ __launch_bounds__(256, 2) void attn_mfma_kernel(
    const ushort* __restrict__ qn,   // [B][N][CI]
    const ushort* __restrict__ kn,   // [B][N][CI]
    const ushort* __restrict__ vm,   // [B][CI][N]
    ushort* __restrict__ Opart,      // [4][B][N][CI] bf16 (unnormalized)
    float* __restrict__ lbuf)        // [4][B][N] row sums
{
    __shared__ __align__(16) ushort smem[35328];   // 70656 B
    ushort* Qs = smem;                 // [128][SQK] (staging only)
    ushort* Ps = smem;                 // [128][SPV] (aliases Qs after hoist)
    ushort* Ks = smem + 17408;         // [64][SQK]
    ushort* Vt = smem + 26112;         // [128][SPV]

    const int b     = blockIdx.z;
    const int chunk = blockIdx.y;
    const int i0    = blockIdx.x * 128;
    const int jbase = chunk * JCHUNK;
    const int t     = threadIdx.x;
    const int wv    = t >> 6;
    const int lane  = t & 63;
    const int n32   = lane & 31;
    const int h     = lane >> 5;
    const int pr    = wv >> 1;         // pair: q in [64pr, 64pr+64)
    const int dv    = wv & 1;          // j-half (S) / d-half (PV)
    const int qb0   = 64 * pr;
    const int jb0   = 32 * dv;
    const int db0   = 64 * dv;

    const ushort* qb = qn + ((size_t)b * N_ + i0) * CI_;
    const ushort* kb = kn + (size_t)b * N_ * CI_;
    const ushort* vb = vm + (size_t)b * CI_ * N_;

    // ---- stage Q once
    #pragma unroll
    for (int r = 0; r < 8; r++) {
        int idx = t + 256 * r;
        int row = idx >> 4, ch = idx & 15;
        *(uint4*)&Qs[row * SQK + ch * 8] = *(const uint4*)&qb[(size_t)row * CI_ + ch * 8];
    }
    block_sync_lds();

    // hoist aQ for both q-strips of the pair
    s16x8 aQ[2][8];
    #pragma unroll
    for (int st = 0; st < 2; st++)
        #pragma unroll
        for (int kk = 0; kk < 8; kk++)
            aQ[st][kk] = *(const s16x8*)&Qs[(qb0 + 32 * st + n32) * SQK + 16 * kk + 8 * h];

    s16x8 vones;
    #pragma unroll
    for (int u = 0; u < 8; u++) vones[u] = (short)0x3F80;

    f32x16 Oacc[2][2], Lacc[2];
    #pragma unroll
    for (int st = 0; st < 2; st++) {
        #pragma unroll
        for (int d2 = 0; d2 < 2; d2++)
            #pragma unroll
            for (int e = 0; e < 16; e++) Oacc[st][d2][e] = 0.f;
        #pragma unroll
        for (int e = 0; e < 16; e++) Lacc[st][e] = 0.f;
    }

    // ---- prefetch first j-tile
    uint4 pfK[4], pfV[4];
    #pragma unroll
    for (int r = 0; r < 4; r++) {
        int idx = t + 256 * r;
        int row = idx >> 4, ch = idx & 15;
        pfK[r] = *(const uint4*)&kb[(size_t)(jbase + row) * CI_ + ch * 8];
    }
    #pragma unroll
    for (int r = 0; r < 4; r++) {
        int idx = t + 256 * r;
        int d = idx >> 3, ch = idx & 7;
        pfV[r] = *(const uint4*)&vb[(size_t)d * N_ + jbase + ch * 8];
    }

    for (int jt = jbase; jt < jbase + JCHUNK; jt += 64) {
        block_sync_lds();   // barrier 1: prev tile's LDS reads retired
        #pragma unroll
        for (int r = 0; r < 4; r++) {
            int idx = t + 256 * r;
            int row = idx >> 4, ch = idx & 15;
            *(uint4*)&Ks[row * SQK + ch * 8] = pfK[r];
        }
        #pragma unroll
        for (int r = 0; r < 4; r++) {
            int idx = t + 256 * r;
            int d = idx >> 3, ch = idx & 7;
            *(uint4*)&Vt[d * SPV + ch * 8] = pfV[r];
        }
        // prefetch next tile (pinned before barrier 2; in flight during compute)
        if (jt + 64 < jbase + JCHUNK) {
            const ushort* ksrc = kb + (size_t)(jt + 64) * CI_;
            #pragma unroll
            for (int r = 0; r < 4; r++) {
                int idx = t + 256 * r;
                int row = idx >> 4, ch = idx & 15;
                pfK[r] = *(const uint4*)&ksrc[(size_t)row * CI_ + ch * 8];
            }
            #pragma unroll
            for (int r = 0; r < 4; r++) {
                int idx = t + 256 * r;
                int d = idx >> 3, ch = idx & 7;
                pfV[r] = *(const uint4*)&vb[(size_t)d * N_ + jt + 64 + ch * 8];
            }
        }
        block_sync_lds();   // barrier 2: K/V visible

        // ---- S: S(64q x 32j), bK shared across the 2 q-strips
        f32x16 S0, S1;
        #pragma unroll
        for (int e = 0; e < 16; e++) { S0[e] = 0.f; S1[e] = 0.f; }
        #pragma unroll
        for (int kk = 0; kk < 8; kk++) {
            s16x8 bK = *(const s16x8*)&Ks[(jb0 + n32) * SQK + 16 * kk + 8 * h];
            S0 = __builtin_amdgcn_mfma_f32_32x32x16_bf16(aQ[0][kk], bK, S0, 0, 0, 0);
            S1 = __builtin_amdgcn_mfma_f32_32x32x16_bf16(aQ[1][kk], bK, S1, 0, 0, 0);
        }

        // ---- P = exp(S) -> pair-shared LDS [q][j]
        #pragma unroll
        for (int rg = 0; rg < 16; rg++) {
            int R = (rg & 3) + 8 * (rg >> 2) + 4 * h;
            Ps[(qb0 + R) * SPV + jb0 + n32]      = f2bf(__expf(S0[rg]));
            Ps[(qb0 + 32 + R) * SPV + jb0 + n32] = f2bf(__expf(S1[rg]));
        }
        block_sync_lds();   // barrier 3: P visible across the pair

        // ---- PV + L: O(64q x 64d) over j 0..63; bV shared across q-strips
        s16x8 aP[2][4];
        #pragma unroll
        for (int st = 0; st < 2; st++)
            #pragma unroll
            for (int kk = 0; kk < 4; kk++)
                aP[st][kk] = *(const s16x8*)&Ps[(qb0 + 32 * st + n32) * SPV + 16 * kk + 8 * h];
        if (dv == 0) {
            #pragma unroll
            for (int st = 0; st < 2; st++)
                #pragma unroll
                for (int kk = 0; kk < 4; kk++)
                    Lacc[st] = __builtin_amdgcn_mfma_f32_32x32x16_bf16(aP[st][kk], vones, Lacc[st], 0, 0, 0);
        }
        #pragma unroll
        for (int d2 = 0; d2 < 2; d2++) {
            #pragma unroll
            for (int kk = 0; kk < 4; kk++) {
                s16x8 bV = *(const s16x8*)&Vt[(db0 + 32 * d2 + n32) * SPV + 16 * kk + 8 * h];
                Oacc[0][d2] = __builtin_amdgcn_mfma_f32_32x32x16_bf16(aP[0][kk], bV, Oacc[0][d2], 0, 0, 0);
                Oacc[1][d2] = __builtin_amdgcn_mfma_f32_32x32x16_bf16(aP[1][kk], bV, Oacc[1][d2], 0, 0, 0);
            }
        }
    }

    // ---- epilogue: unnormalized O -> [b][n][d] bf16; l -> lbuf (even waves)
    ushort* Ob = Opart + (size_t)chunk * (B_ * N_ * CI_) + ((size_t)b * N_ + i0) * CI_;
    #pragma unroll
    for (int st = 0; st < 2; st++) {
        #pragma unroll
        for (int rg = 0; rg < 16; rg++) {
            int R = (rg & 3) + 8 * (rg >> 2) + 4 * h;
            int q = qb0 + 32 * st + R;
            #pragma unroll
            for (int d2 = 0; d2 < 2; d2++)
                Ob[(size_t)q * CI_ + db0 + 32 * d2 + n32] = f2bf(Oacc[st][d2][rg]);
        }
    }
    if (dv == 0 && n32 == 0) {
        #pragma unroll
        for (int st = 0; st < 2; st++)
            #pragma unroll
            for (int rg = 0; rg < 16; rg++) {
                int R = (rg & 3) + 8 * (rg >> 2) + 4 * h;
                lbuf[((size_t)chunk * B_ + b) * N_ + i0 + qb0 + 32 * st + R] = Lacc[st][rg];
            }
    }
}

// ---------------------------------------------------------------------------
// Output GEMM (bf16 MFMA), M-tile 64 (round-6 version), fused 4-chunk combine.
// Grid (N/64, C/64, B).
// ---------------------------------------------------------------------------
__global__ __launch_bounds__(256) void outgemm_kernel(
    const ushort* __restrict__ Wobf, const float* __restrict__ bo,
    const ushort* __restrict__ Opart, const float* __restrict__ lbuf,
    const float* __restrict__ x, float* __restrict__ out)
{
    __shared__ ushort Ws[64][72];
    __shared__ ushort Ys[64][72];
    const int b = blockIdx.z, m0 = blockIdx.y * 64, n0 = blockIdx.x * 64;
    const int t = threadIdx.x, wv = t >> 6, lane = t & 63;
    const int g4 = lane >> 4, ln = lane & 15;
    const ushort* Wsrc = Wobf + (size_t)m0 * CI_;
    const size_t cs = (size_t)B_ * N_ * CI_;   // chunk stride

    f32x4 acc[4];
    #pragma unroll
    for (int i = 0; i < 4; i++) acc[i] = (f32x4){0.f, 0.f, 0.f, 0.f};

    for (int k0 = 0; k0 < CI_; k0 += 64) {
        block_sync_lds();
        #pragma unroll
        for (int r = 0; r < 2; r++) {
            int idx = t + 256 * r;
            int row = idx >> 3, k8 = (idx & 7) * 8;
            *(uint4*)&Ws[row][k8] = *(const uint4*)&Wsrc[(size_t)row * CI_ + k0 + k8];
            size_t obase = ((size_t)b * N_ + n0 + row) * CI_ + k0 + k8;
            float lsum = 0.f;
            #pragma unroll
            for (int c = 0; c < 4; c++)
                lsum += lbuf[((size_t)c * B_ + b) * N_ + n0 + row];
            float inv = 1.0f / lsum;
            ushort o0[8], o1[8], o2[8], o3[8], yo[8];
            *(uint4*)o0 = *(const uint4*)&Opart[obase];
            *(uint4*)o1 = *(const uint4*)&Opart[cs + obase];
            *(uint4*)o2 = *(const uint4*)&Opart[2 * cs + obase];
            *(uint4*)o3 = *(const uint4*)&Opart[3 * cs + obase];
            #pragma unroll
            for (int u = 0; u < 8; u++)
                yo[u] = f2bf((bf2f(o0[u]) + bf2f(o1[u]) + bf2f(o2[u]) + bf2f(o3[u])) * inv);
            *(uint4*)&Ys[row][k8] = *(uint4*)yo;
        }
        block_sync_lds();
        #pragma unroll
        for (int kk = 0; kk < 2; kk++) {
            s16x8 aW = *(const s16x8*)&Ws[16 * wv + ln][32 * kk + 8 * g4];
            #pragma unroll
            for (int nt = 0; nt < 4; nt++) {
                s16x8 bY = *(const s16x8*)&Ys[16 * nt + ln][32 * kk + 8 * g4];
                acc[nt] = __builtin_amdgcn_mfma_f32_16x16x32_bf16(aW, bY, acc[nt], 0, 0, 0);
            }
        }
    }

    float* outb = out + (size_t)b * C_ * N_;
    const float* xb = x + (size_t)b * C_ * N_;
    #pragma unroll
    for (int r = 0; r < 4; r++) {
        int m = m0 + 16 * wv + 4 * g4 + r;
        float bi = bo[m];
        #pragma unroll
        for (int nt = 0; nt < 4; nt++) {
            size_t idx = (size_t)m * N_ + n0 + 16 * nt + ln;
            outb[idx] = acc[nt][r] + bi + xb[idx];
        }
    }
}

// ---------------------------------------------------------------------------
extern "C" void kernel_launch(void* const* d_in, const int* in_sizes, int n_in,
                              void* d_out, int out_size, void* d_ws, size_t ws_size,
                              hipStream_t stream) {
    const float* x  = (const float*)d_in[0];
    const float* Wg = (const float*)d_in[1];
    const float* bg = (const float*)d_in[2];
    const float* Wt = (const float*)d_in[3];
    const float* bt = (const float*)d_in[4];
    const float* Wp = (const float*)d_in[5];
    const float* bp = (const float*)d_in[6];
    const float* Wo = (const float*)d_in[7];
    const float* bo = (const float*)d_in[8];
    float* out = (float*)d_out;

    // ws layout (bytes). xT (8 MB) dead after proj; Opart (16 MB) aliases it.
    char* w = (char*)d_ws;
    ushort* xT    = (ushort*)w;                   // [B][N][C]  bf16, 8 MB
    ushort* Opart = (ushort*)w;                   // [4][B][N][CI] bf16, 16 MB
    ushort* g     = (ushort*)(w + 16777216);      // [B][CI][N] bf16, 4 MB
    ushort* tht   = (ushort*)(w + 20971520);      // [B][N][CI] bf16, 4 MB
    ushort* pht   = (ushort*)(w + 25165824);      // [B][N][CI] bf16, 4 MB
    ushort* Wcat  = (ushort*)(w + 29360128);      // [384][256] bf16
    ushort* Wobf  = (ushort*)(w + 29556736);      // [256][128] bf16
    float*  bcat  = (float*) (w + 29622272);      // [384]
    float*  lbuf  = (float*) (w + 29623808);      // [4][B][N] fp32, 256 KB

    dim3 blk(256);
    wcast_kernel<<<512, blk, 0, stream>>>(Wg, Wt, Wp, Wo, bg, bt, bp, Wcat, Wobf, bcat);
    xt_kernel<<<dim3(N_ / 64, C_ / 64, B_), blk, 0, stream>>>(x, xT);
    proj_kernel<<<dim3(N_ / 64, 6, B_), blk, 0, stream>>>(Wcat, bcat, xT, g, tht, pht);
    attn_mfma_kernel<<<dim3(N_ / 128, 4, B_), blk, 0, stream>>>(tht, pht, g, Opart, lbuf);
    outgemm_kernel<<<dim3(N_ / 64, C_ / 64, B_), blk, 0, stream>>>(Wobf, bo, Opart, lbuf, x, out);
}